// Round 1
// baseline (495.551 us; speedup 1.0000x reference)
//
#include <hip/hip_runtime.h>

namespace {

constexpr int T_STEPS = 1000;
constexpr int NB      = 4096;
constexpr float LOG2E = 1.4426950408889634f;

__device__ __forceinline__ float fexp2(float x) { return __builtin_amdgcn_exp2f(x); }
__device__ __forceinline__ float frcp(float x)  { return __builtin_amdgcn_rcpf(x); }

// One element (batch row) per 16 lanes. Lane q (0..15): unit u=q&7, half hlf=q>>3.
// hlf=0 lane computes gates (i_u, f_u); hlf=1 lane computes (g_u, o_u).
// All state (weights, h, c) lives in registers; h is rebroadcast with width-16 shuffles.
// No LDS, no __syncthreads anywhere.
__global__ __launch_bounds__(256, 1)
void lstm_fused_kernel(
    const float* __restrict__ state, const float* __restrict__ dist,
    const float* __restrict__ e1W1, const float* __restrict__ e1b1,
    const float* __restrict__ e1W2, const float* __restrict__ e1b2,
    const float* __restrict__ e2W1, const float* __restrict__ e2b1,
    const float* __restrict__ e2W2, const float* __restrict__ e2b2,
    const float* __restrict__ Wih0, const float* __restrict__ Whh0,
    const float* __restrict__ bih0, const float* __restrict__ bhh0,
    const float* __restrict__ Wih1, const float* __restrict__ Whh1,
    const float* __restrict__ bih1, const float* __restrict__ bhh1,
    const float* __restrict__ decW, const float* __restrict__ decb,
    const float* __restrict__ finW, const float* __restrict__ finb,
    const float* __restrict__ fin2W, const float* __restrict__ fin2b,
    float* __restrict__ out)
{
    const int tid = (int)threadIdx.x;
    const int q   = tid & 15;
    const int n   = blockIdx.x * 16 + (tid >> 4);
    const int u   = q & 7;
    const int hlf = q >> 3;
    const int r0  = hlf * 16 + u;   // row of gate A (i_u or g_u)
    const int r1  = r0 + 8;         // row of gate B (f_u or o_u)

    // ---- per-lane weight rows (stay in VGPRs for the whole kernel) ----
    float wx0a[8], wh0a[8], wx0b[8], wh0b[8];
    float wx1a[8], wh1a[8], wx1b[8], wh1b[8];
#pragma unroll
    for (int k = 0; k < 8; ++k) {
        wx0a[k] = Wih0[r0 * 8 + k]; wh0a[k] = Whh0[r0 * 8 + k];
        wx0b[k] = Wih0[r1 * 8 + k]; wh0b[k] = Whh0[r1 * 8 + k];
        wx1a[k] = Wih1[r0 * 8 + k]; wh1a[k] = Whh1[r0 * 8 + k];
        wx1b[k] = Wih1[r1 * 8 + k]; wh1b[k] = Whh1[r1 * 8 + k];
    }
    const float b0a = bih0[r0] + bhh0[r0], b0b = bih0[r1] + bhh0[r1];
    const float b1a = bih1[r0] + bhh1[r0], b1b = bih1[r1] + bhh1[r1];

    // decoder weights: lanes q&3 hold dec row (q&3); each lane owns output u (mu u<4, sigma u>=4)
    float dwr[8];
    const int dr = q & 3;
#pragma unroll
    for (int k = 0; k < 8; ++k) dwr[k] = decW[dr * 8 + k];
    const float dbr = decb[dr];
    float fw[4]; float fb;
    {
        const float* Wp = (u < 4) ? finW : fin2W;
        const float* bp = (u < 4) ? finb : fin2b;
        const int oo = u & 3;
#pragma unroll
        for (int d = 0; d < 4; ++d) fw[d] = Wp[oo * 4 + d];
        fb = bp[oo];
    }

    // branchless activation constants: hlf=0 -> sigmoid, hlf=1 -> tanh (=2*sig(2x)-1) for gate A
    const float sclA = hlf ? (-2.0f * LOG2E) : (-LOG2E);
    const float mulA = hlf ? 2.0f : 1.0f;
    const float addA = hlf ? -1.0f : 0.0f;

    // ---------------- encoders (one-time, replicated per lane) ----------------
    float h0a[8], h1a[8], c0, c1;
    {
        float s[16];
#pragma unroll
        for (int k = 0; k < 16; ++k) s[k] = state[n * 16 + k];
        float hm[4];
#pragma unroll
        for (int m = 0; m < 4; ++m) {
            float a = e1b1[m];
#pragma unroll
            for (int k = 0; k < 16; ++k) a = fmaf(s[k], e1W1[m * 16 + k], a);
            hm[m] = fmaxf(a, 0.0f);
        }
#pragma unroll
        for (int j = 0; j < 8; ++j) {
            float a = e1b2[j], b = e1b2[8 + j];
#pragma unroll
            for (int m = 0; m < 4; ++m) {
                a = fmaf(hm[m], e1W2[j * 4 + m], a);
                b = fmaf(hm[m], e1W2[(8 + j) * 4 + m], b);
            }
            h0a[j] = fmaxf(a, 0.0f);   // layer0 h init, unit j
            h1a[j] = fmaxf(b, 0.0f);   // layer1 h init, unit j
        }
#pragma unroll
        for (int m = 0; m < 4; ++m) {
            float a = e2b1[m];
#pragma unroll
            for (int k = 0; k < 16; ++k) a = fmaf(s[k], e2W1[m * 16 + k], a);
            hm[m] = fmaxf(a, 0.0f);
        }
        float a = e2b2[u], b = e2b2[8 + u];
#pragma unroll
        for (int m = 0; m < 4; ++m) {
            a = fmaf(hm[m], e2W2[u * 4 + m], a);
            b = fmaf(hm[m], e2W2[(8 + u) * 4 + m], b);
        }
        c0 = fmaxf(a, 0.0f);           // layer0 c init, own unit
        c1 = fmaxf(b, 0.0f);           // layer1 c init, own unit
    }

    // ---------------- x stream + output pointers ----------------
    const float4* dp = reinterpret_cast<const float4*>(dist) + (size_t)n * 2;
    constexpr size_t TS4 = (size_t)NB * 2;                // float4 stride per timestep
    float* outp = out + ((u < 4) ? ((size_t)n * 4 + u)
                                 : ((size_t)T_STEPS * NB * 4 + (size_t)n * 4 + (u - 4)));
    const bool doStore = (q < 8);

    float4 xA0 = dp[0],   xA1 = dp[1];      // t = 0
    float4 xB0 = dp[TS4], xB1 = dp[TS4 + 1];// t = 1

    auto step = [&](const float4& lo, const float4& hi, float* op) {
        const float x[8] = {lo.x, lo.y, lo.z, lo.w, hi.x, hi.y, hi.z, hi.w};
        // ----- layer 0: x-part first (x prefetched), then h-part -----
        float aa = b0a, ab = b0b;
#pragma unroll
        for (int k = 0; k < 8; ++k) { aa = fmaf(x[k], wx0a[k], aa); ab = fmaf(x[k], wx0b[k], ab); }
#pragma unroll
        for (int k = 0; k < 8; ++k) { aa = fmaf(h0a[k], wh0a[k], aa); ab = fmaf(h0a[k], wh0b[k], ab); }
        float a0 = fmaf(frcp(1.0f + fexp2(aa * sclA)), mulA, addA); // sig(i) | tanh(g)
        float a1 = frcp(1.0f + fexp2(ab * -LOG2E));                 // sig(f) | sig(o)
        float p0 = __shfl_xor(a0, 8, 16);
        float p1 = __shfl_xor(a1, 8, 16);
        float si = hlf ? p0 : a0, sf = hlf ? p1 : a1;
        float tg = hlf ? a0 : p0, so = hlf ? a1 : p1;
        c0 = fmaf(sf, c0, si * tg);
        float th = fmaf(frcp(1.0f + fexp2(c0 * (-2.0f * LOG2E))), 2.0f, -1.0f);
        float hu = so * th;
#pragma unroll
        for (int k = 0; k < 8; ++k) h0a[k] = __shfl(hu, k, 16);
        // ----- layer 1: h-part first (h1a is local), x-part (= fresh h0a) last,
        //       giving the h0 broadcast shuffles time to land -----
        aa = b1a; ab = b1b;
#pragma unroll
        for (int k = 0; k < 8; ++k) { aa = fmaf(h1a[k], wh1a[k], aa); ab = fmaf(h1a[k], wh1b[k], ab); }
#pragma unroll
        for (int k = 0; k < 8; ++k) { aa = fmaf(h0a[k], wx1a[k], aa); ab = fmaf(h0a[k], wx1b[k], ab); }
        a0 = fmaf(frcp(1.0f + fexp2(aa * sclA)), mulA, addA);
        a1 = frcp(1.0f + fexp2(ab * -LOG2E));
        p0 = __shfl_xor(a0, 8, 16);
        p1 = __shfl_xor(a1, 8, 16);
        si = hlf ? p0 : a0; sf = hlf ? p1 : a1;
        tg = hlf ? a0 : p0; so = hlf ? a1 : p1;
        c1 = fmaf(sf, c1, si * tg);
        th = fmaf(frcp(1.0f + fexp2(c1 * (-2.0f * LOG2E))), 2.0f, -1.0f);
        hu = so * th;
#pragma unroll
        for (int k = 0; k < 8; ++k) h1a[k] = __shfl(hu, k, 16);
        // ----- decoder + heads -----
        float da = dbr;
#pragma unroll
        for (int k = 0; k < 8; ++k) da = fmaf(h1a[k], dwr[k], da);
        da = fmaxf(da, 0.0f);
        const float d0 = __shfl(da, 0, 16), d1 = __shfl(da, 1, 16);
        const float d2 = __shfl(da, 2, 16), d3 = __shfl(da, 3, 16);
        float o = fb;
        o = fmaf(d0, fw[0], o); o = fmaf(d1, fw[1], o);
        o = fmaf(d2, fw[2], o); o = fmaf(d3, fw[3], o);
        if (doStore) *op = o;
    };

    for (int t = 0; t < T_STEPS; t += 2) {
        // prefetch t+2 / t+3 (clamped at the tail to a safe in-bounds address)
        const size_t oA = (size_t)((t + 2 < T_STEPS) ? (t + 2) : 0) * TS4;
        float4 nA0 = dp[oA], nA1 = dp[oA + 1];
        step(xA0, xA1, outp);
        outp += (size_t)NB * 4;
        const size_t oB = (size_t)((t + 3 < T_STEPS) ? (t + 3) : 0) * TS4;
        float4 nB0 = dp[oB], nB1 = dp[oB + 1];
        step(xB0, xB1, outp);
        outp += (size_t)NB * 4;
        xA0 = nA0; xA1 = nA1; xB0 = nB0; xB1 = nB1;
    }
}

} // namespace

extern "C" void kernel_launch(void* const* d_in, const int* in_sizes, int n_in,
                              void* d_out, int out_size, void* d_ws, size_t ws_size,
                              hipStream_t stream) {
    const float* state = (const float*)d_in[0];
    const float* dist  = (const float*)d_in[1];
    const float* e1W1  = (const float*)d_in[2];
    const float* e1b1  = (const float*)d_in[3];
    const float* e1W2  = (const float*)d_in[4];
    const float* e1b2  = (const float*)d_in[5];
    const float* e2W1  = (const float*)d_in[6];
    const float* e2b1  = (const float*)d_in[7];
    const float* e2W2  = (const float*)d_in[8];
    const float* e2b2  = (const float*)d_in[9];
    const float* Wih0  = (const float*)d_in[10];
    const float* Whh0  = (const float*)d_in[11];
    const float* bih0  = (const float*)d_in[12];
    const float* bhh0  = (const float*)d_in[13];
    const float* Wih1  = (const float*)d_in[14];
    const float* Whh1  = (const float*)d_in[15];
    const float* bih1  = (const float*)d_in[16];
    const float* bhh1  = (const float*)d_in[17];
    const float* decW  = (const float*)d_in[18];
    const float* decb  = (const float*)d_in[19];
    const float* finW  = (const float*)d_in[20];
    const float* finb  = (const float*)d_in[21];
    const float* fin2W = (const float*)d_in[22];
    const float* fin2b = (const float*)d_in[23];
    float* outp = (float*)d_out;

    lstm_fused_kernel<<<dim3(NB / 16), dim3(256), 0, stream>>>(
        state, dist,
        e1W1, e1b1, e1W2, e1b2,
        e2W1, e2b1, e2W2, e2b2,
        Wih0, Whh0, bih0, bhh0,
        Wih1, Whh1, bih1, bhh1,
        decW, decb, finW, finb, fin2W, fin2b,
        outp);
}